// Round 6
// baseline (475.043 us; speedup 1.0000x reference)
//
#include <hip/hip_runtime.h>

// Problem constants
#define B_    32
#define Q_    900
#define T_    1024
#define C_    365
#define M_    (B_*Q_)     // 28800 rows
#define PB_   (Q_*C_)     // 328500 prob entries per batch
#define NSEL  300
#define NBINS 8192
#define CAP   4096
#define MARGIN_BINS 10            // 0.73 value margin >> 2*eps(bf16 coarse)  [proven R11]
#define HIST_INV (8192.0f/600.0f) // fixed range [0,600)
#define NT    23                  // ceil(365/16) n-tiles (fused fallback)
#define NTILES_B 24               // swizzled B tiles incl. fully-clamped tile 23
#define MBLK  32                  // m-rows per gemm block
#define MISC_BLOCKS 1024          // covers B_*NBINS = 262144 init elements

typedef __attribute__((ext_vector_type(8))) short bf16x8;
typedef __attribute__((ext_vector_type(4))) float f32x4;

// ---------- helpers ----------
__device__ __forceinline__ unsigned enc_f(float f) {
    unsigned u = __float_as_uint(f);
    return (u & 0x80000000u) ? ~u : (u | 0x80000000u);
}
__device__ __forceinline__ float dec_f(unsigned u) {
    unsigned b = (u & 0x80000000u) ? (u & 0x7FFFFFFFu) : ~u;
    return __uint_as_float(b);
}
__device__ __forceinline__ unsigned short f2bf(float f) { // RNE
    unsigned u = __float_as_uint(f);
    unsigned r = u + 0x7FFFu + ((u >> 16) & 1u);
    return (unsigned short)(r >> 16);
}
__device__ __forceinline__ int coarse_bin(float v) {
    int bin = (int)(v * HIST_INV);
    return bin < 0 ? 0 : (bin > NBINS - 1 ? NBINS - 1 : bin);
}
__device__ __forceinline__ float sigmoid_coarse(float x) {
    return __builtin_amdgcn_rcpf(1.f + __expf(-x));  // EXACT formula of proven coarse path
}

// ---------- 1) init v6: misc only (hist/cnt zero, pmb fallback, swizzled B) ----------
// R5: As is no longer materialized (sigmoid+staging fused into gemm) -> init is tiny.
__global__ __launch_bounds__(256) void init_cvt_kernel(unsigned* __restrict__ hist,
                                                       unsigned* __restrict__ cnt,
                                                       const float* __restrict__ pmap,
                                                       unsigned short* __restrict__ pmb,
                                                       unsigned short* __restrict__ pbsw) {
    const int g0 = blockIdx.x * 256 + threadIdx.x;
    if (g0 < B_ * NBINS) hist[g0] = 0u;
    if (g0 < B_) cnt[g0] = 0u;
    if (g0 < (C_ * T_) / 4) {           // pmb for the fallback path (linear bf16 B)
        const float4 v = ((const float4*)pmap)[g0];
        ushort4 o;
        o.x = f2bf(v.x); o.y = f2bf(v.y); o.z = f2bf(v.z); o.w = f2bf(v.w);
        ((ushort4*)pmb)[g0] = o;
    }
    if (pbsw != nullptr && g0 < NTILES_B * 32 * 64 * 2) {  // 98304 swizzled-B half-units
        const int h  = g0 & 1;
        const int ln = (g0 >> 1) & 63;
        const int kb = (g0 >> 7) & 31;
        const int s  = g0 >> 12;
        int r = s * 16 + (ln & 15);
        if (r > C_ - 1) r = C_ - 1;                      // bake row clamp into layout
        const int c = kb * 32 + ((ln >> 4) & 3) * 8 + h * 4;
        const float4 v = *(const float4*)(pmap + (size_t)r * T_ + c);
        ushort4 o;
        o.x = f2bf(v.x); o.y = f2bf(v.y); o.z = f2bf(v.z); o.w = f2bf(v.w);
        *(ushort4*)(pbsw + ((size_t)(s * 32 + kb) * 64 + ln) * 8 + h * 4) = o;
    }
}

// ---------- 2) gemm v6: LDS-staged fused-sigmoid GEMM, 32 m-rows/block ----------
// R5 model: v5's 16-row blocks re-read all B from L2 per block -> 1.38 GB L2 traffic
// (~40us floor) and As costs 59MB write (init) + 59MB read (gemm). Fix: read A fp32
// row-coalesced, sigmoid in-flight, stage bf16 fragments in a bank-XOR'd LDS tile,
// MFMA from LDS. 32 rows/block halves B traffic; As workspace eliminated.
// K staged in two halves; global kb order 0..31 preserved => acc bit-identical to v5.
// A fragment = f2bf(sigmoid_coarse(A[row][kb*32+quad*8 ..+8])) — same values as before.
__global__ __launch_bounds__(256) void gemm_fused_lds_kernel(const float* __restrict__ A,
                                                             const unsigned short* __restrict__ Bsw,
                                                             float* __restrict__ prob) {
    __shared__ unsigned short at[MBLK * 512];   // 32 KB: [32 rows][64 units][8 elems] per K-half
    const int t = threadIdx.x;
    const int lane = t & 63;
    const int wave = t >> 6;
    const int col  = lane & 15;
    const int quad = lane >> 4;
    const int s0 = wave * 6;
    const int m0 = blockIdx.x * MBLK;

    const unsigned short* bp = Bsw + ((size_t)s0 * 2048 + lane) * 8;

    f32x4 acc[2][6] = {};

    for (int h = 0; h < 2; ++h) {
        // ---- stage: 32 rows x 512 cols fp32 -> sigmoid -> bf16 LDS (unit-XOR swizzle) ----
        #pragma unroll
        for (int i = 0; i < 16; ++i) {
            const int idx = i * 256 + t;            // 0..4095
            const int r   = idx >> 7;               // 128 float4 per half-row
            const int c4  = idx & 127;
            const float4 v = *(const float4*)(A + (size_t)(m0 + r) * T_ + h * 512 + c4 * 4);
            ushort4 o;
            o.x = f2bf(sigmoid_coarse(v.x));
            o.y = f2bf(sigmoid_coarse(v.y));
            o.z = f2bf(sigmoid_coarse(v.z));
            o.w = f2bf(sigmoid_coarse(v.w));
            const int u = (c4 >> 1) ^ (r & 7);      // bank-spread swizzle (bijective per row)
            *(ushort4*)(at + (r * 64 + u) * 8 + (c4 & 1) * 4) = o;
        }
        __syncthreads();

        // ---- compute: 16 kb-steps, 2 m-sub-tiles x 6 n-tiles per wave ----
        for (int kb = 0; kb < 16; ++kb) {
            const int up = (kb * 4 + quad) ^ (col & 7);     // (16+col)&7 == col&7
            const bf16x8 a0 = *(const bf16x8*)(at + (col * 64 + up) * 8);
            const bf16x8 a1 = *(const bf16x8*)(at + ((16 + col) * 64 + up) * 8);
            const int kbg = h * 16 + kb;
            #pragma unroll
            for (int j = 0; j < 6; ++j) {
                const bf16x8 bf_ = *(const bf16x8*)(bp + (size_t)j * 16384 + (size_t)kbg * 512);
                acc[0][j] = __builtin_amdgcn_mfma_f32_16x16x32_bf16(a0, bf_, acc[0][j], 0, 0, 0);
                acc[1][j] = __builtin_amdgcn_mfma_f32_16x16x32_bf16(a1, bf_, acc[1][j], 0, 0, 0);
            }
        }
        __syncthreads();
    }

    // ---- epilogue: stores only. C/D: col=lane&15, row=quad*4+reg (unchanged mapping). ----
    #pragma unroll
    for (int mm = 0; mm < 2; ++mm) {
        const int mbase = m0 + mm * 16 + quad * 4;
        #pragma unroll
        for (int j = 0; j < 6; ++j) {
            const int c = (s0 + j) * 16 + col;
            if (c < C_) {
                #pragma unroll
                for (int r = 0; r < 4; r++) {
                    prob[(size_t)(mbase + r) * C_ + c] = acc[mm][j][r];
                }
            }
        }
    }
}

// ---------- 2c) histogram pass v6: 4 lane-interleaved sub-hists (less atomic serialization) ----------
// R5 model: prob is sharply peaked -> whole waves hit the same bin -> ~64-way LDS
// same-address atomic serialization dominated the 32us. 4 sub-hists cut it ~4x.
// Packed u16 pairs; per-block adds <= ceil(PB_/16)=20532 so summed halves can't carry.
__global__ __launch_bounds__(256) void hist_kernel(const float* __restrict__ prob,
                                                   unsigned* __restrict__ hist) {
    __shared__ unsigned lh[4][NBINS / 2];  // 64 KB
    const int b = blockIdx.x >> 4, part = blockIdx.x & 15;
    const int sub = threadIdx.x & 3;
    for (int i = threadIdx.x; i < 4 * (NBINS / 2); i += 256) ((unsigned*)lh)[i] = 0u;
    __syncthreads();
    const float* p = prob + (size_t)b * PB_;
    for (int i = part * 256 + threadIdx.x; i < PB_; i += 16 * 256) {
        const int bin = coarse_bin(p[i]);
        atomicAdd(&lh[sub][bin >> 1], 1u << ((bin & 1) * 16));
    }
    __syncthreads();
    for (int i = threadIdx.x; i < NBINS / 2; i += 256) {
        const unsigned v = lh[0][i] + lh[1][i] + lh[2][i] + lh[3][i];  // no carry (<=20532)
        if (v & 0xFFFFu) atomicAdd(&hist[b * NBINS + 2 * i],     v & 0xFFFFu);
        if (v >> 16)     atomicAdd(&hist[b * NBINS + 2 * i + 1], v >> 16);
    }
}

// ---------- 2b) fallback: v1 fused-sigmoid GEMM (verbatim, proven 509us path) ----------
__global__ __launch_bounds__(256) void gemm_hist_fused_kernel(const float* __restrict__ A,
                                                              const unsigned short* __restrict__ Pb,
                                                              float* __restrict__ prob,
                                                              unsigned* __restrict__ hist) {
    __shared__ unsigned lh[NBINS];  // 32 KB
    const int lane = threadIdx.x & 63;
    const int wave = threadIdx.x >> 6;
    const int col  = lane & 15;
    const int quad = lane >> 4;
    const int m0 = blockIdx.x * 64;
    const int b0 = m0 / Q_;

    for (int i = threadIdx.x; i < NBINS; i += 256) lh[i] = 0u;
    __syncthreads();

    const float* arow = A + (size_t)(m0 + wave * 16 + col) * T_ + quad * 8;
    const unsigned short* bbase = Pb + (size_t)col * T_ + quad * 8;
    const unsigned short* blast = Pb + (size_t)(col < 13 ? 352 + col : 364) * T_ + quad * 8;

    f32x4 acc[NT] = {};

    for (int k0 = 0; k0 < T_; k0 += 32) {
        const float4 a0 = *(const float4*)(arow + k0);
        const float4 a1 = *(const float4*)(arow + k0 + 4);
        const float av[8] = {a0.x, a0.y, a0.z, a0.w, a1.x, a1.y, a1.z, a1.w};
        bf16x8 af;
        #pragma unroll
        for (int j = 0; j < 8; j++) {
            const float sg = __builtin_amdgcn_rcpf(1.f + __expf(-av[j]));
            af[j] = (short)f2bf(sg);
        }
        const unsigned short* bk = bbase + k0;
        #pragma unroll
        for (int s = 0; s < NT - 1; s++) {
            const bf16x8 bf_ = *(const bf16x8*)bk;
            bk += 16 * T_;
            acc[s] = __builtin_amdgcn_mfma_f32_16x16x32_bf16(af, bf_, acc[s], 0, 0, 0);
        }
        {
            const bf16x8 bf_ = *(const bf16x8*)(blast + k0);
            acc[NT - 1] = __builtin_amdgcn_mfma_f32_16x16x32_bf16(af, bf_, acc[NT - 1], 0, 0, 0);
        }
    }

    const int mbase = m0 + wave * 16 + quad * 4;
    #pragma unroll
    for (int s = 0; s < NT; s++) {
        const int c = s * 16 + col;
        if (c < C_) {
            #pragma unroll
            for (int r = 0; r < 4; r++) {
                const int m = mbase + r;
                const float v = acc[s][r];
                prob[(size_t)m * C_ + c] = v;
                const int bin = coarse_bin(v);
                const int bm = m / Q_;
                if (bm == b0) atomicAdd(&lh[bin], 1u);
                else          atomicAdd(&hist[bm * NBINS + bin], 1u);
            }
        }
    }
    __syncthreads();
    for (int i = threadIdx.x; i < NBINS; i += 256)
        if (lh[i]) atomicAdd(&hist[b0 * NBINS + i], lh[i]);
}

// ---------- 3) threshold bin (minus safety margin for coarse bf16 error) ----------
__global__ __launch_bounds__(256) void select_kernel(const unsigned* __restrict__ hist,
                                                     unsigned* __restrict__ binStar) {
    const int b = blockIdx.x;
    const int t = threadIdx.x;
    __shared__ unsigned csum[256], pref[256];
    const unsigned* h = hist + b * NBINS;
    const int lo = NBINS - 32 * (t + 1);
    unsigned s = 0;
    for (int i = 0; i < 32; i++) s += h[lo + i];
    csum[t] = s;
    __syncthreads();
    if (t == 0) {
        unsigned acc = 0;
        for (int i = 0; i < 256; i++) { pref[i] = acc; acc += csum[i]; }
    }
    __syncthreads();
    const unsigned above = pref[t];
    if (above < NSEL && above + csum[t] >= NSEL) {
        unsigned cum = above;
        for (int bin = NBINS - 32 * t - 1; bin >= lo; bin--) {
            cum += h[bin];
            if (cum >= NSEL) {
                int bs = bin - MARGIN_BINS;
                binStar[b] = (unsigned)(bs < 0 ? 0 : bs);
                break;
            }
        }
    }
}

// ---------- 4) collect candidate indices with bin >= b* ----------
__global__ __launch_bounds__(256) void collect_kernel(const float* __restrict__ prob,
                                                      const unsigned* __restrict__ binStar,
                                                      unsigned* __restrict__ cnt,
                                                      unsigned* __restrict__ candIdx) {
    const int b = blockIdx.x >> 4, part = blockIdx.x & 15;
    const int bstar = (int)binStar[b];
    const float* p = prob + (size_t)b * PB_;
    for (int i = part * 256 + threadIdx.x; i < PB_; i += 16 * 256) {
        if (coarse_bin(p[i]) >= bstar) {
            const unsigned pos = atomicAdd(&cnt[b], 1u);
            if (pos < CAP) candIdx[b * CAP + pos] = (unsigned)i;
        }
    }
}

// ---------- 5) refine: bit-replicate np.einsum fp32 SOP kernel (SSE3 baseline) ----------
// PROVEN in R10 — do not alter semantics.
__global__ __launch_bounds__(256) void refine_kernel(const float* __restrict__ logits,
                                                     const float* __restrict__ pmap,
                                                     const unsigned* __restrict__ cnt,
                                                     const unsigned* __restrict__ candIdx,
                                                     float* __restrict__ candVal) {
    const int b   = blockIdx.x >> 4;
    const int blk = blockIdx.x & 15;
    const int wave = threadIdx.x >> 6;
    const int lane = threadIdx.x & 63;
    const int sub  = lane >> 2;                 // 16 candidates per wave
    const int k    = lane & 3;                  // SSE lane / chain index 0..3
    const int gw = (blk * 4 + wave) * 16 + sub;
    unsigned n = cnt[b];
    if (n > CAP) n = CAP;
    for (unsigned j = gw; j < n; j += 1024) {
        const unsigned idx = candIdx[b * CAP + j];
        const int q = (int)(idx / C_);
        const int c = (int)(idx % C_);
        const float* arow = logits + ((size_t)b * Q_ + q) * T_;
        const float* prow = pmap + (size_t)c * T_;
        float acc = 0.f;
        for (int i = 0; i < 256; i++) {
            const int t = 4 * i + k;
            const float x = arow[t];
            const float e = (float)exp(-(double)x);     // correctly-rounded fp32 exp
            const float d = __fadd_rn(1.0f, e);
            const float sg = __fdiv_rn(1.0f, d);
            acc = __fadd_rn(acc, __fmul_rn(sg, prow[t])); // mul-round, add-round (no fma)
        }
        const float c0 = __shfl(acc, sub * 4 + 0, 64);
        const float c1 = __shfl(acc, sub * 4 + 1, 64);
        const float c2 = __shfl(acc, sub * 4 + 2, 64);
        const float c3 = __shfl(acc, sub * 4 + 3, 64);
        if (k == 0) {
            candVal[b * CAP + j] = __fadd_rn(__fadd_rn(c0, c1), __fadd_rn(c2, c3));
        }
    }
}

// ---------- 6) bitonic sort on (fp32 value desc, idx asc) + epilogue ----------
__global__ __launch_bounds__(512) void sort_out_kernel(const float* __restrict__ candVal,
                                                       const unsigned* __restrict__ candIdx,
                                                       const unsigned* __restrict__ cnt,
                                                       const float* __restrict__ boxesIn,
                                                       const float* __restrict__ tsz,
                                                       float* __restrict__ out) {
    __shared__ unsigned long long keys[CAP]; // 32 KB
    const int b = blockIdx.x;
    const int t = threadIdx.x;
    unsigned n = cnt[b];
    if (n > CAP) n = CAP;
    unsigned p = 512;
    while (p < n) p <<= 1;

    for (unsigned i = t; i < p; i += 512) {
        unsigned long long kk = 0ull;  // below any real key
        if (i < n) {
            const unsigned u = enc_f(candVal[b * CAP + i]);
            const unsigned idx = candIdx[b * CAP + i];
            kk = ((unsigned long long)u << 32) | (unsigned long long)(0xFFFFFFFFu - idx);
        }
        keys[i] = kk;
    }
    __syncthreads();

    for (unsigned k = 2; k <= p; k <<= 1) {
        for (unsigned j = k >> 1; j > 0; j >>= 1) {
            for (unsigned i = t; i < p; i += 512) {
                const unsigned ixj = i ^ j;
                if (ixj > i) {
                    const unsigned long long a = keys[i];
                    const unsigned long long c = keys[ixj];
                    const bool up = ((i & k) == 0); // descending overall
                    if (up ? (a < c) : (a > c)) { keys[i] = c; keys[ixj] = a; }
                }
            }
            __syncthreads();
        }
    }

    if (t < NSEL) {
        const unsigned long long k = keys[t];
        const float score = dec_f((unsigned)(k >> 32));
        const unsigned idx = 0xFFFFFFFFu - (unsigned)(k & 0xFFFFFFFFull);
        const int q = (int)(idx / C_);
        const int lab = (int)(idx % C_);

        out[b * NSEL + t] = score;                   // scores (32,300)
        out[B_ * NSEL + b * NSEL + t] = (float)lab;  // labels (32,300)

        const float* pb = boxesIn + ((size_t)b * Q_ + q) * 4;
        const float cx = pb[0], cy = pb[1], w = pb[2], h = pb[3];
        const float img_h = tsz[b * 2 + 0];
        const float img_w = tsz[b * 2 + 1];
        float* bo = out + 2 * B_ * NSEL + ((size_t)b * NSEL + t) * 4;
        bo[0] = (cx - 0.5f * w) * img_w;
        bo[1] = (cy - 0.5f * h) * img_h;
        bo[2] = (cx + 0.5f * w) * img_w;
        bo[3] = (cy + 0.5f * h) * img_h;
    }
}

extern "C" void kernel_launch(void* const* d_in, const int* in_sizes, int n_in,
                              void* d_out, int out_size, void* d_ws, size_t ws_size,
                              hipStream_t stream) {
    const float* logits = (const float*)d_in[0]; // (32,900,1024)
    const float* pboxes = (const float*)d_in[1]; // (32,900,4)
    const float* pmap   = (const float*)d_in[2]; // (365,1024)
    const float* tsz    = (const float*)d_in[3]; // (32,2)
    float* out = (float*)d_out;

    // workspace layout (~45.7 MB; all segments 16B-aligned). As eliminated in R5.
    float*          prob    = (float*)d_ws;                          // 42,048,000 B
    unsigned*       hist    = (unsigned*)(prob + (size_t)M_ * C_);   // 1,048,576 B
    unsigned*       cnt     = hist + B_ * NBINS;                     // 128 B
    unsigned*       binStar = cnt + 32;                              // 128 B
    unsigned*       candIdx = binStar + 32;                          // 524,288 B
    float*          candVal = (float*)(candIdx + B_ * CAP);          // 524,288 B
    unsigned short* pmb     = (unsigned short*)(candVal + B_ * CAP); // 747,520 B
    unsigned short* pbsw    = pmb + (size_t)C_ * T_;                 // 786,432 B (swizzled B, 24 tiles)

    // STRICT gate: the fast path needs workspace through pbsw.
    const size_t need_sw = (size_t)((char*)pbsw - (char*)d_ws)
                         + (size_t)NTILES_B * 32 * 64 * 8 * sizeof(unsigned short);
    const bool useSw = (d_ws != nullptr) && (ws_size >= need_sw);

    init_cvt_kernel<<<MISC_BLOCKS, 256, 0, stream>>>(hist, cnt, pmap, pmb,
                                                     useSw ? pbsw : nullptr);
    if (useSw) {
        gemm_fused_lds_kernel<<<M_ / MBLK, 256, 0, stream>>>(logits, pbsw, prob);
        hist_kernel<<<B_ * 16, 256, 0, stream>>>(prob, hist);
    } else {
        gemm_hist_fused_kernel<<<M_ / 64, 256, 0, stream>>>(logits, pmb, prob, hist);
    }
    select_kernel<<<B_, 256, 0, stream>>>(hist, binStar);
    collect_kernel<<<B_ * 16, 256, 0, stream>>>(prob, binStar, cnt, candIdx);
    refine_kernel<<<B_ * 16, 256, 0, stream>>>(logits, pmap, cnt, candIdx, candVal);
    sort_out_kernel<<<B_, 512, 0, stream>>>(candVal, candIdx, cnt, pboxes, tsz, out);
}

// Round 7
// 419.012 us; speedup vs baseline: 1.1337x; 1.1337x over previous
//
#include <hip/hip_runtime.h>

// Problem constants
#define B_    32
#define Q_    900
#define T_    1024
#define C_    365
#define M_    (B_*Q_)     // 28800 rows
#define PB_   (Q_*C_)     // 328500 prob entries per batch
#define NSEL  300
#define NBINS 8192
#define CAP   4096
#define MARGIN_BINS 10            // 0.73 value margin >> 2*eps(bf16 coarse)  [proven R11]
#define HIST_INV (8192.0f/600.0f) // fixed range [0,600)
#define NT    23                  // ceil(365/16) n-tiles (fused fallback)
#define NTILES_B 24               // swizzled B tiles incl. fully-clamped tile 23
#define MT_   (M_/16)             // 1800 m-tiles
#define MBLK  32                  // m-rows per gemm block (R7: 2 tiles/block halves B L2 traffic)
#define MISC_BLOCKS 1024          // covers B_*NBINS = 262144 init elements

typedef __attribute__((ext_vector_type(8))) short bf16x8;
typedef __attribute__((ext_vector_type(4))) float f32x4;

// ---------- helpers ----------
__device__ __forceinline__ unsigned enc_f(float f) {
    unsigned u = __float_as_uint(f);
    return (u & 0x80000000u) ? ~u : (u | 0x80000000u);
}
__device__ __forceinline__ float dec_f(unsigned u) {
    unsigned b = (u & 0x80000000u) ? (u & 0x7FFFFFFFu) : ~u;
    return __uint_as_float(b);
}
__device__ __forceinline__ unsigned short f2bf(float f) { // RNE
    unsigned u = __float_as_uint(f);
    unsigned r = u + 0x7FFFu + ((u >> 16) & 1u);
    return (unsigned short)(r >> 16);
}
__device__ __forceinline__ int coarse_bin(float v) {
    int bin = (int)(v * HIST_INV);
    return bin < 0 ? 0 : (bin > NBINS - 1 ? NBINS - 1 : bin);
}
__device__ __forceinline__ float sigmoid_coarse(float x) {
    return __builtin_amdgcn_rcpf(1.f + __expf(-x));  // EXACT formula of proven coarse path
}

// R6 lesson: fusing sigmoid+staging INTO the gemm (stage->barrier->MFMA) regressed
// 70->161us — the serial VALU phase can't overlap compute at 20% occupancy. The
// R5 split (streaming init builds As at >2TB/s; gemm reads 1KB bursts) is faster.

// ---------- 1) init v5 (proven): per-m-tile LDS-bounce sigmoid+swizzle ----------
// Block mt reads 64KB of A contiguously, builds the tile's 32KB As segment in LDS
// (bank-swizzled), dumps as 8 contiguous 4KB bursts. Blocks >= tileBlocks do misc.
__global__ __launch_bounds__(256) void init_cvt_kernel(unsigned* __restrict__ hist,
                                                       unsigned* __restrict__ cnt,
                                                       const float* __restrict__ pmap,
                                                       unsigned short* __restrict__ pmb,
                                                       unsigned short* __restrict__ pbsw,
                                                       const float* __restrict__ A,
                                                       unsigned short* __restrict__ Asw,
                                                       int tileBlocks) {
    __shared__ unsigned short tile[16384];  // 32 KB = one m-tile of As
    const int t = threadIdx.x;

    if ((int)blockIdx.x < tileBlocks) {
        const int mt = blockIdx.x;
        const float4* arow = (const float4*)A + (size_t)mt * 4096; // 16 rows x 256 f4
        #pragma unroll
        for (int i = 0; i < 16; ++i) {              // row i: 256 threads x float4 = 4KB burst
            const float4 v = arow[i * 256 + t];
            ushort4 o;
            o.x = f2bf(sigmoid_coarse(v.x));
            o.y = f2bf(sigmoid_coarse(v.y));
            o.z = f2bf(sigmoid_coarse(v.z));
            o.w = f2bf(sigmoid_coarse(v.w));
            // c = 4t: kb = t>>3, q = (t>>1)&3, elem-half = t&1
            const int u = ((t >> 3) * 64) + (((t >> 1) & 3) * 16) + i;
            const int p = u ^ (((t >> 1) & 3) | (((t >> 3) & 1) << 2));
            *(ushort4*)(tile + p * 8 + (t & 1) * 4) = o;
        }
        __syncthreads();
        const uint4* src = (const uint4*)tile;
        uint4* dst = (uint4*)Asw + (size_t)mt * 2048;
        #pragma unroll
        for (int j = 0; j < 8; ++j)                 // 8 x 4KB contiguous bursts
            dst[j * 256 + t] = src[j * 256 + t];
        return;
    }

    // ---- misc init (verbatim semantics) ----
    const int g0 = ((int)blockIdx.x - tileBlocks) * 256 + t;
    if (g0 < B_ * NBINS) hist[g0] = 0u;
    if (g0 < B_) cnt[g0] = 0u;
    if (g0 < (C_ * T_) / 4) {           // pmb for the fallback path (linear bf16 B)
        const float4 v = ((const float4*)pmap)[g0];
        ushort4 o;
        o.x = f2bf(v.x); o.y = f2bf(v.y); o.z = f2bf(v.z); o.w = f2bf(v.w);
        ((ushort4*)pmb)[g0] = o;
    }
    if (pbsw != nullptr && g0 < NTILES_B * 32 * 64 * 2) {  // 98304 swizzled-B half-units
        const int h  = g0 & 1;
        const int ln = (g0 >> 1) & 63;
        const int kb = (g0 >> 7) & 31;
        const int s  = g0 >> 12;
        int r = s * 16 + (ln & 15);
        if (r > C_ - 1) r = C_ - 1;                      // bake row clamp into layout
        const int c = kb * 32 + ((ln >> 4) & 3) * 8 + h * 4;
        const float4 v = *(const float4*)(pmap + (size_t)r * T_ + c);
        ushort4 o;
        o.x = f2bf(v.x); o.y = f2bf(v.y); o.z = f2bf(v.z); o.w = f2bf(v.w);
        *(ushort4*)(pbsw + ((size_t)(s * 32 + kb) * 64 + ln) * 8 + h * 4) = o;
    }
}

// ---------- 2) gemm v7: swizzled operands, 1KB-burst loads, 32 m-rows/block ----------
// R5 model: 16-row blocks re-read all 768KB of B per block -> 1.38GB L2 traffic
// (~40us floor of the 70us). 2 m-tiles per block halve that; per-m-row MFMA
// sequence and operand values identical to v5 => prob bit-identical.
__global__ __launch_bounds__(256) void gemm_kernel(const unsigned short* __restrict__ Asw,
                                                   const unsigned short* __restrict__ Bsw,
                                                   float* __restrict__ prob) {
    const int lane = threadIdx.x & 63;
    const int wave = threadIdx.x >> 6;
    const int col  = lane & 15;
    const int quad = lane >> 4;
    const int s0 = wave * 6;

    const unsigned short* ap = Asw + (size_t)blockIdx.x * 32768;   // 2 tiles x 16384 shorts
    const int le = (lane ^ quad) * 8;        // even-kb swizzled lane offset (shorts)
    const int lo = ((lane ^ quad) ^ 4) * 8;  // odd-kb
    const unsigned short* bp = Bsw + ((size_t)s0 * 2048 + lane) * 8;

    f32x4 acc[2][6] = {};
    for (int kb = 0; kb < 32; ++kb) {
        const int sel = (kb & 1) ? lo : le;
        const bf16x8 a0 = *(const bf16x8*)(ap + kb * 512 + sel);
        const bf16x8 a1 = *(const bf16x8*)(ap + 16384 + kb * 512 + sel);
        #pragma unroll
        for (int j = 0; j < 6; j++) {
            const bf16x8 bf_ = *(const bf16x8*)(bp + (size_t)j * 16384 + (size_t)kb * 512);
            acc[0][j] = __builtin_amdgcn_mfma_f32_16x16x32_bf16(a0, bf_, acc[0][j], 0, 0, 0);
            acc[1][j] = __builtin_amdgcn_mfma_f32_16x16x32_bf16(a1, bf_, acc[1][j], 0, 0, 0);
        }
    }

    // epilogue: stores only. C/D: col=lane&15, row=quad*4+reg (unchanged mapping).
    #pragma unroll
    for (int mm = 0; mm < 2; ++mm) {
        const int mbase = blockIdx.x * MBLK + mm * 16 + quad * 4;
        #pragma unroll
        for (int j = 0; j < 6; j++) {
            const int c = (s0 + j) * 16 + col;
            if (c < C_) {
                #pragma unroll
                for (int r = 0; r < 4; r++) {
                    prob[(size_t)(mbase + r) * C_ + c] = acc[mm][j][r];
                }
            }
        }
    }
}

// ---------- 2c) histogram pass (R5-proven): stream prob, per-batch-slice LDS hist ----------
__global__ __launch_bounds__(256) void hist_kernel(const float* __restrict__ prob,
                                                   unsigned* __restrict__ hist) {
    __shared__ unsigned lh[NBINS];  // 32 KB, plain u32 bins
    const int b = blockIdx.x >> 4, part = blockIdx.x & 15;
    for (int i = threadIdx.x; i < NBINS; i += 256) lh[i] = 0u;
    __syncthreads();
    const float* p = prob + (size_t)b * PB_;
    for (int i = part * 256 + threadIdx.x; i < PB_; i += 16 * 256) {
        atomicAdd(&lh[coarse_bin(p[i])], 1u);
    }
    __syncthreads();
    for (int i = threadIdx.x; i < NBINS; i += 256)
        if (lh[i]) atomicAdd(&hist[b * NBINS + i], lh[i]);
}

// ---------- 2b) fallback: v1 fused-sigmoid GEMM (verbatim, proven 509us path) ----------
__global__ __launch_bounds__(256) void gemm_hist_fused_kernel(const float* __restrict__ A,
                                                              const unsigned short* __restrict__ Pb,
                                                              float* __restrict__ prob,
                                                              unsigned* __restrict__ hist) {
    __shared__ unsigned lh[NBINS];  // 32 KB
    const int lane = threadIdx.x & 63;
    const int wave = threadIdx.x >> 6;
    const int col  = lane & 15;
    const int quad = lane >> 4;
    const int m0 = blockIdx.x * 64;
    const int b0 = m0 / Q_;

    for (int i = threadIdx.x; i < NBINS; i += 256) lh[i] = 0u;
    __syncthreads();

    const float* arow = A + (size_t)(m0 + wave * 16 + col) * T_ + quad * 8;
    const unsigned short* bbase = Pb + (size_t)col * T_ + quad * 8;
    const unsigned short* blast = Pb + (size_t)(col < 13 ? 352 + col : 364) * T_ + quad * 8;

    f32x4 acc[NT] = {};

    for (int k0 = 0; k0 < T_; k0 += 32) {
        const float4 a0 = *(const float4*)(arow + k0);
        const float4 a1 = *(const float4*)(arow + k0 + 4);
        const float av[8] = {a0.x, a0.y, a0.z, a0.w, a1.x, a1.y, a1.z, a1.w};
        bf16x8 af;
        #pragma unroll
        for (int j = 0; j < 8; j++) {
            const float sg = __builtin_amdgcn_rcpf(1.f + __expf(-av[j]));
            af[j] = (short)f2bf(sg);
        }
        const unsigned short* bk = bbase + k0;
        #pragma unroll
        for (int s = 0; s < NT - 1; s++) {
            const bf16x8 bf_ = *(const bf16x8*)bk;
            bk += 16 * T_;
            acc[s] = __builtin_amdgcn_mfma_f32_16x16x32_bf16(af, bf_, acc[s], 0, 0, 0);
        }
        {
            const bf16x8 bf_ = *(const bf16x8*)(blast + k0);
            acc[NT - 1] = __builtin_amdgcn_mfma_f32_16x16x32_bf16(af, bf_, acc[NT - 1], 0, 0, 0);
        }
    }

    const int mbase = m0 + wave * 16 + quad * 4;
    #pragma unroll
    for (int s = 0; s < NT; s++) {
        const int c = s * 16 + col;
        if (c < C_) {
            #pragma unroll
            for (int r = 0; r < 4; r++) {
                const int m = mbase + r;
                const float v = acc[s][r];
                prob[(size_t)m * C_ + c] = v;
                const int bin = coarse_bin(v);
                const int bm = m / Q_;
                if (bm == b0) atomicAdd(&lh[bin], 1u);
                else          atomicAdd(&hist[bm * NBINS + bin], 1u);
            }
        }
    }
    __syncthreads();
    for (int i = threadIdx.x; i < NBINS; i += 256)
        if (lh[i]) atomicAdd(&hist[b0 * NBINS + i], lh[i]);
}

// ---------- 3) threshold bin (minus safety margin for coarse bf16 error) ----------
__global__ __launch_bounds__(256) void select_kernel(const unsigned* __restrict__ hist,
                                                     unsigned* __restrict__ binStar) {
    const int b = blockIdx.x;
    const int t = threadIdx.x;
    __shared__ unsigned csum[256], pref[256];
    const unsigned* h = hist + b * NBINS;
    const int lo = NBINS - 32 * (t + 1);
    unsigned s = 0;
    for (int i = 0; i < 32; i++) s += h[lo + i];
    csum[t] = s;
    __syncthreads();
    if (t == 0) {
        unsigned acc = 0;
        for (int i = 0; i < 256; i++) { pref[i] = acc; acc += csum[i]; }
    }
    __syncthreads();
    const unsigned above = pref[t];
    if (above < NSEL && above + csum[t] >= NSEL) {
        unsigned cum = above;
        for (int bin = NBINS - 32 * t - 1; bin >= lo; bin--) {
            cum += h[bin];
            if (cum >= NSEL) {
                int bs = bin - MARGIN_BINS;
                binStar[b] = (unsigned)(bs < 0 ? 0 : bs);
                break;
            }
        }
    }
}

// ---------- 4) collect candidate indices with bin >= b* ----------
__global__ __launch_bounds__(256) void collect_kernel(const float* __restrict__ prob,
                                                      const unsigned* __restrict__ binStar,
                                                      unsigned* __restrict__ cnt,
                                                      unsigned* __restrict__ candIdx) {
    const int b = blockIdx.x >> 4, part = blockIdx.x & 15;
    const int bstar = (int)binStar[b];
    const float* p = prob + (size_t)b * PB_;
    for (int i = part * 256 + threadIdx.x; i < PB_; i += 16 * 256) {
        if (coarse_bin(p[i]) >= bstar) {
            const unsigned pos = atomicAdd(&cnt[b], 1u);
            if (pos < CAP) candIdx[b * CAP + pos] = (unsigned)i;
        }
    }
}

// ---------- 5) refine: bit-replicate np.einsum fp32 SOP kernel (SSE3 baseline) ----------
// PROVEN in R10 — do not alter semantics.
__global__ __launch_bounds__(256) void refine_kernel(const float* __restrict__ logits,
                                                     const float* __restrict__ pmap,
                                                     const unsigned* __restrict__ cnt,
                                                     const unsigned* __restrict__ candIdx,
                                                     float* __restrict__ candVal) {
    const int b   = blockIdx.x >> 4;
    const int blk = blockIdx.x & 15;
    const int wave = threadIdx.x >> 6;
    const int lane = threadIdx.x & 63;
    const int sub  = lane >> 2;                 // 16 candidates per wave
    const int k    = lane & 3;                  // SSE lane / chain index 0..3
    const int gw = (blk * 4 + wave) * 16 + sub;
    unsigned n = cnt[b];
    if (n > CAP) n = CAP;
    for (unsigned j = gw; j < n; j += 1024) {
        const unsigned idx = candIdx[b * CAP + j];
        const int q = (int)(idx / C_);
        const int c = (int)(idx % C_);
        const float* arow = logits + ((size_t)b * Q_ + q) * T_;
        const float* prow = pmap + (size_t)c * T_;
        float acc = 0.f;
        for (int i = 0; i < 256; i++) {
            const int t = 4 * i + k;
            const float x = arow[t];
            const float e = (float)exp(-(double)x);     // correctly-rounded fp32 exp
            const float d = __fadd_rn(1.0f, e);
            const float sg = __fdiv_rn(1.0f, d);
            acc = __fadd_rn(acc, __fmul_rn(sg, prow[t])); // mul-round, add-round (no fma)
        }
        const float c0 = __shfl(acc, sub * 4 + 0, 64);
        const float c1 = __shfl(acc, sub * 4 + 1, 64);
        const float c2 = __shfl(acc, sub * 4 + 2, 64);
        const float c3 = __shfl(acc, sub * 4 + 3, 64);
        if (k == 0) {
            candVal[b * CAP + j] = __fadd_rn(__fadd_rn(c0, c1), __fadd_rn(c2, c3));
        }
    }
}

// ---------- 6) bitonic sort on (fp32 value desc, idx asc) + epilogue ----------
__global__ __launch_bounds__(512) void sort_out_kernel(const float* __restrict__ candVal,
                                                       const unsigned* __restrict__ candIdx,
                                                       const unsigned* __restrict__ cnt,
                                                       const float* __restrict__ boxesIn,
                                                       const float* __restrict__ tsz,
                                                       float* __restrict__ out) {
    __shared__ unsigned long long keys[CAP]; // 32 KB
    const int b = blockIdx.x;
    const int t = threadIdx.x;
    unsigned n = cnt[b];
    if (n > CAP) n = CAP;
    unsigned p = 512;
    while (p < n) p <<= 1;

    for (unsigned i = t; i < p; i += 512) {
        unsigned long long kk = 0ull;  // below any real key
        if (i < n) {
            const unsigned u = enc_f(candVal[b * CAP + i]);
            const unsigned idx = candIdx[b * CAP + i];
            kk = ((unsigned long long)u << 32) | (unsigned long long)(0xFFFFFFFFu - idx);
        }
        keys[i] = kk;
    }
    __syncthreads();

    for (unsigned k = 2; k <= p; k <<= 1) {
        for (unsigned j = k >> 1; j > 0; j >>= 1) {
            for (unsigned i = t; i < p; i += 512) {
                const unsigned ixj = i ^ j;
                if (ixj > i) {
                    const unsigned long long a = keys[i];
                    const unsigned long long c = keys[ixj];
                    const bool up = ((i & k) == 0); // descending overall
                    if (up ? (a < c) : (a > c)) { keys[i] = c; keys[ixj] = a; }
                }
            }
            __syncthreads();
        }
    }

    if (t < NSEL) {
        const unsigned long long k = keys[t];
        const float score = dec_f((unsigned)(k >> 32));
        const unsigned idx = 0xFFFFFFFFu - (unsigned)(k & 0xFFFFFFFFull);
        const int q = (int)(idx / C_);
        const int lab = (int)(idx % C_);

        out[b * NSEL + t] = score;                   // scores (32,300)
        out[B_ * NSEL + b * NSEL + t] = (float)lab;  // labels (32,300)

        const float* pb = boxesIn + ((size_t)b * Q_ + q) * 4;
        const float cx = pb[0], cy = pb[1], w = pb[2], h = pb[3];
        const float img_h = tsz[b * 2 + 0];
        const float img_w = tsz[b * 2 + 1];
        float* bo = out + 2 * B_ * NSEL + ((size_t)b * NSEL + t) * 4;
        bo[0] = (cx - 0.5f * w) * img_w;
        bo[1] = (cy - 0.5f * h) * img_h;
        bo[2] = (cx + 0.5f * w) * img_w;
        bo[3] = (cy + 0.5f * h) * img_h;
    }
}

extern "C" void kernel_launch(void* const* d_in, const int* in_sizes, int n_in,
                              void* d_out, int out_size, void* d_ws, size_t ws_size,
                              hipStream_t stream) {
    const float* logits = (const float*)d_in[0]; // (32,900,1024)
    const float* pboxes = (const float*)d_in[1]; // (32,900,4)
    const float* pmap   = (const float*)d_in[2]; // (365,1024)
    const float* tsz    = (const float*)d_in[3]; // (32,2)
    float* out = (float*)d_out;

    // workspace layout (~104.7 MB with swizzled operands; all segments 16B-aligned)
    float*          prob    = (float*)d_ws;                          // 42,048,000 B
    unsigned*       hist    = (unsigned*)(prob + (size_t)M_ * C_);   // 1,048,576 B
    unsigned*       cnt     = hist + B_ * NBINS;                     // 128 B
    unsigned*       binStar = cnt + 32;                              // 128 B
    unsigned*       candIdx = binStar + 32;                          // 524,288 B
    float*          candVal = (float*)(candIdx + B_ * CAP);          // 524,288 B
    unsigned short* pmb     = (unsigned short*)(candVal + B_ * CAP); // 747,520 B
    unsigned short* Asw     = pmb + (size_t)C_ * T_;                 // 58,982,400 B (swizzled A)
    unsigned short* pbsw    = Asw + (size_t)M_ * T_;                 // 786,432 B (swizzled B, 24 tiles)

    // STRICT gate: the swizzled fast-path runs ONLY if the workspace provably holds it.
    const size_t need_sw = (size_t)((char*)pbsw - (char*)d_ws)
                         + (size_t)NTILES_B * 32 * 64 * 8 * sizeof(unsigned short);
    const bool useSw = (d_ws != nullptr) && (ws_size >= need_sw);
    const int tileBlocks = useSw ? MT_ : 0;

    init_cvt_kernel<<<tileBlocks + MISC_BLOCKS, 256, 0, stream>>>(
        hist, cnt, pmap, pmb,
        useSw ? pbsw : nullptr,
        logits,
        useSw ? Asw : nullptr,
        tileBlocks);
    if (useSw) {
        gemm_kernel<<<M_ / MBLK, 256, 0, stream>>>(Asw, pbsw, prob);
        hist_kernel<<<B_ * 16, 256, 0, stream>>>(prob, hist);
    } else {
        gemm_hist_fused_kernel<<<M_ / 64, 256, 0, stream>>>(logits, pmb, prob, hist);
    }
    select_kernel<<<B_, 256, 0, stream>>>(hist, binStar);
    collect_kernel<<<B_ * 16, 256, 0, stream>>>(prob, binStar, cnt, candIdx);
    refine_kernel<<<B_ * 16, 256, 0, stream>>>(logits, pmap, cnt, candIdx, candVal);
    sort_out_kernel<<<B_, 512, 0, stream>>>(candVal, candIdx, cnt, pboxes, tsz, out);
}